// Round 6
// baseline (485.306 us; speedup 1.0000x reference)
//
#include <hip/hip_runtime.h>
#include <stdint.h>

typedef __bf16 bf16_t;
typedef __bf16 bf16x8 __attribute__((ext_vector_type(8)));
typedef float f32x4 __attribute__((ext_vector_type(4)));

#define EPSV 1e-5f
#define QSCALE 0.08838834764831845f
#define NB 16
#define HWD 1024
#define CIN 2048
#define MID 512
#define QKLD 1024

__device__ __forceinline__ void gl_lds16(const bf16_t* g, void* l) {
    __builtin_amdgcn_global_load_lds(
        (const __attribute__((address_space(1))) uint32_t*)g,
        (__attribute__((address_space(3))) uint32_t*)l, 16, 0, 0);
}

__device__ __forceinline__ f32x4 mfma16(bf16x8 a, bf16x8 b, f32x4 c) {
    return __builtin_amdgcn_mfma_f32_16x16x32_bf16(a, b, c, 0, 0, 0);
}

// ---------------- prep: weight casts + emb table ----------------
#define PW1 (512*2048)
#define PQK (PW1 + 1024*512)
#define PV  (PQK + 512*512)
#define PW3 (PV  + 2048*512)
#define PE  (PW3 + 1024*128)

__global__ void prep_kernel(const float* __restrict__ conv1_w,
                            const float* __restrict__ qk_w,
                            const float* __restrict__ v_w,
                            const float* __restrict__ pos_h,
                            const float* __restrict__ pos_w,
                            const float* __restrict__ conv3_w,
                            bf16_t* __restrict__ w1b, bf16_t* __restrict__ wqkb,
                            bf16_t* __restrict__ wvb, bf16_t* __restrict__ w3b,
                            float* __restrict__ emb) {
    int stride = gridDim.x * blockDim.x;
    for (int i = blockIdx.x * blockDim.x + threadIdx.x; i < PE; i += stride) {
        if (i < PW1) {
            w1b[i] = (bf16_t)conv1_w[i];
        } else if (i < PQK) {
            int j = i - PW1;
            int row = j >> 9;
            float v = (row < 512) ? qk_w[j] * QSCALE : qk_w[j];
            wqkb[j] = (bf16_t)v;
        } else if (i < PV) {
            int j = i - PQK;
            wvb[j] = (bf16_t)v_w[j];
        } else if (i < PW3) {
            int j = i - PV;
            w3b[j] = (bf16_t)conv3_w[j];
        } else {
            int j = i - PW3;
            int y = j >> 7, d = j & 127;
            emb[j] = pos_h[(y >> 5) * 128 + d] + pos_w[(y & 31) * 128 + d];
        }
    }
}

// ---------------- transpose x: [n][c][hw] f32 -> [n][hw][c] bf16 ----------------
__global__ void transpose_x_kernel(const float* __restrict__ x, bf16_t* __restrict__ xt) {
    __shared__ uint32_t tileT[64][20];   // [hw][c-pair], pad 16->20
    const int n = blockIdx.z;
    const int c0 = blockIdx.x * 32;
    const int hw0 = blockIdx.y * 64;
    const int t = threadIdx.x;

    const int cp = t >> 4;            // 0..15 c-pair
    const int hw4 = (t & 15) * 4;     // 0..60
    const float* p0 = x + ((size_t)n * CIN + c0 + 2 * cp) * HWD + hw0 + hw4;
    const float4 a = *(const float4*)p0;
    const float4 b = *(const float4*)(p0 + HWD);
    float av[4] = {a.x, a.y, a.z, a.w};
    float bv[4] = {b.x, b.y, b.z, b.w};
#pragma unroll
    for (int i = 0; i < 4; ++i) {
        uint16_t lo = __builtin_bit_cast(uint16_t, (bf16_t)av[i]);
        uint16_t hi = __builtin_bit_cast(uint16_t, (bf16_t)bv[i]);
        tileT[hw4 + i][cp] = (uint32_t)lo | ((uint32_t)hi << 16);
    }
    __syncthreads();
    const int hw = t >> 2;            // 0..63
    const int seg = (t & 3) * 4;      // u32 seg
    uint4 v = *(const uint4*)&tileT[hw][seg];
    *(uint4*)(xt + ((size_t)n * HWD + hw0 + hw) * CIN + c0 + 2 * seg) = v;
}

// ---------------- generic BMx128 bf16 gemm_bt, BK=64, swizzled LDS ----------------
// C[m][n] = sum_k A[m][k]*B[n][k]; A:[M][K], B:[N][K] K-contiguous bf16.
// BM in {128, 256}. 4 waves in 2x2; per-wave tile (BM/2)x64.
// Rationale (R6): the 128^2 compute phase reads 1 KiB LDS per MFMA
// (16 FLOP/B) -> capped by ~85 B/cy/CU LDS read throughput (~840 TF
// structural). BM=256 gives 42.7 FLOP/B -> LDS no longer the cap.
// K-loop: single-buffered 2-barrier (explicit dbuf measured null R5).
// LDS tiles BMx64 + 128x64, rows = 8 granules of 16B,
// phys_gran = gran ^ (row&7) (swizzle on global source; dest lane-linear).
// Epilogue: LDS-transposed -> coalesced 16B stores + vectorized params.
// EPI 1: BN+ReLU by col -> bf16; EPI 2: +emb cols>=512 -> bf16;
// EPI 3: BN by row + residual e4 + ReLU -> f32; EPI 4: plain bf16.
// launch_bounds: BM=128: (256,3) VGPR 64, 32K LDS; BM=256: (256,2)
// (acc 8x4 f32x4 = 128 VGPR; ~200 live; do NOT force higher - R3 spill).
template <int EPI, int BM>
__global__ __launch_bounds__(256, (BM == 128 ? 3 : 2))
void gemm_bt(const bf16_t* __restrict__ A, long long aStride,
             const bf16_t* __restrict__ B, long long bStride,
             int K, int ldc,
             const float* __restrict__ e0, const float* __restrict__ e1,
             const float* __restrict__ e2, const float* __restrict__ e3,
             const float* __restrict__ e4, long long e4Stride,
             void* __restrict__ C, long long cStride) {
    constexpr int WM = BM / 2;          // per-wave M span
    constexpr int MI = WM / 16;         // A fragments / acc rows (4 or 8)
    __shared__ char smem[BM * 128 + 16384];   // As (BM*64*2) | Bs (16K)
    bf16_t* As = (bf16_t*)smem;
    bf16_t* Bs = (bf16_t*)(smem + BM * 128);
    const int lane = threadIdx.x & 63;
    const int wave = threadIdx.x >> 6;
    const int tN = blockIdx.x * 128, tM = blockIdx.y * BM;
    const int b = blockIdx.z;
    A += (size_t)b * aStride;
    B += (size_t)b * bStride;

    const int wm = (wave >> 1) * WM, wn = (wave & 1) * 64;
    const int lrow = lane & 15, quad = lane >> 4;
    const int srow = lane >> 3;          // 0..7 row within 8-row group
    const int sgr = lane & 7;            // phys granule (lane-linear dest)
    const int lg = sgr ^ srow;           // logical granule at source

    f32x4 acc[MI][4];
    const f32x4 z4 = {0.f, 0.f, 0.f, 0.f};
#pragma unroll
    for (int i = 0; i < MI; ++i)
#pragma unroll
        for (int j = 0; j < 4; ++j) acc[i][j] = z4;

    for (int k0 = 0; k0 < K; k0 += 64) {
        __syncthreads();
#pragma unroll
        for (int j = 0; j < BM / 32; ++j) {      // A: BM/8 row-blocks / 4 waves
            const int blk = wave * (BM / 32) + j;
            const int row = blk * 8 + srow;
            gl_lds16(A + (size_t)(tM + row) * K + k0 + lg * 8,
                     (char*)As + blk * 1024 + lane * 16);
        }
#pragma unroll
        for (int j = 0; j < 4; ++j) {            // B: 16 row-blocks / 4 waves
            const int blk = wave * 4 + j;
            const int row = blk * 8 + srow;
            gl_lds16(B + (size_t)(tN + row) * K + k0 + lg * 8,
                     (char*)Bs + blk * 1024 + lane * 16);
        }
        __syncthreads();
#pragma unroll
        for (int kh = 0; kh < 2; ++kh) {
            bf16x8 af[MI], bfr[4];
#pragma unroll
            for (int t = 0; t < MI; ++t) {
                const int ar = wm + t * 16 + lrow;
                af[t] = *(const bf16x8*)(As + ar * 64 + (((kh * 4 + quad) ^ (ar & 7)) * 8));
            }
#pragma unroll
            for (int t = 0; t < 4; ++t) {
                const int br = wn + t * 16 + lrow;
                bfr[t] = *(const bf16x8*)(Bs + br * 64 + (((kh * 4 + quad) ^ (br & 7)) * 8));
            }
#pragma unroll
            for (int i = 0; i < MI; ++i)
#pragma unroll
                for (int j = 0; j < 4; ++j)
                    acc[i][j] = mfma16(af[i], bfr[j], acc[i][j]);
        }
    }

    // ---------------- LDS-transposed epilogue ----------------
    // per wave: stage 16x64 f32 slice (stride 68 to spread banks),
    // read back 8 consecutive cols/lane, store coalesced 16B.
    __syncthreads();                       // all waves done reading As/Bs
    float* Es = (float*)(smem + wave * 4352);   // 16*68*4 = 4352 B per wave
    const int pr = lane >> 3;              // 0..7  row within pass
    const int pc = (lane & 7) * 8;         // col8 base
    const int gcol = tN + wn + pc;

#pragma unroll
    for (int i = 0; i < MI; ++i) {
#pragma unroll
        for (int j = 0; j < 4; ++j)
#pragma unroll
            for (int r = 0; r < 4; ++r)
                Es[(quad * 4 + r) * 68 + j * 16 + lrow] = acc[i][j][r];
        // wave-synchronous: compiler orders ds_write -> ds_read via lgkmcnt
#pragma unroll
        for (int p = 0; p < 2; ++p) {
            const int lr = p * 8 + pr;
            const int grow = tM + wm + i * 16 + lr;
            float vf[8];
            *(f32x4*)&vf[0] = *(const f32x4*)&Es[lr * 68 + pc];
            *(f32x4*)&vf[4] = *(const f32x4*)&Es[lr * 68 + pc + 4];

            if constexpr (EPI == 1) {
                float gg[8], bt[8], mm[8], vv[8];
                *(f32x4*)&gg[0] = *(const f32x4*)(e0 + gcol);
                *(f32x4*)&gg[4] = *(const f32x4*)(e0 + gcol + 4);
                *(f32x4*)&bt[0] = *(const f32x4*)(e1 + gcol);
                *(f32x4*)&bt[4] = *(const f32x4*)(e1 + gcol + 4);
                *(f32x4*)&mm[0] = *(const f32x4*)(e2 + gcol);
                *(f32x4*)&mm[4] = *(const f32x4*)(e2 + gcol + 4);
                *(f32x4*)&vv[0] = *(const f32x4*)(e3 + gcol);
                *(f32x4*)&vv[4] = *(const f32x4*)(e3 + gcol + 4);
                bf16x8 ob;
#pragma unroll
                for (int c = 0; c < 8; ++c) {
                    float inv = gg[c] * rsqrtf(vv[c] + EPSV);
                    float val = fmaxf(vf[c] * inv + (bt[c] - mm[c] * inv), 0.f);
                    ob[c] = (bf16_t)val;
                }
                bf16_t* Cb = (bf16_t*)C + (size_t)b * cStride;
                *(bf16x8*)(Cb + (size_t)grow * ldc + gcol) = ob;
            } else if constexpr (EPI == 2) {
                bf16x8 ob;
                if (gcol >= 512) {            // wave-uniform
                    float ev[8];
                    const float* ep = e4 + (size_t)grow * 128 + (gcol & 127);
                    *(f32x4*)&ev[0] = *(const f32x4*)ep;
                    *(f32x4*)&ev[4] = *(const f32x4*)(ep + 4);
#pragma unroll
                    for (int c = 0; c < 8; ++c) ob[c] = (bf16_t)(vf[c] + ev[c]);
                } else {
#pragma unroll
                    for (int c = 0; c < 8; ++c) ob[c] = (bf16_t)vf[c];
                }
                bf16_t* Cb = (bf16_t*)C + (size_t)b * cStride;
                *(bf16x8*)(Cb + (size_t)grow * ldc + gcol) = ob;
            } else if constexpr (EPI == 4) {
                bf16x8 ob;
#pragma unroll
                for (int c = 0; c < 8; ++c) ob[c] = (bf16_t)vf[c];
                bf16_t* Cb = (bf16_t*)C + (size_t)b * cStride;
                *(bf16x8*)(Cb + (size_t)grow * ldc + gcol) = ob;
            } else {                          // EPI 3
                float g = e0[grow], bet = e1[grow], mn = e2[grow], vr = e3[grow];
                float inv = g * rsqrtf(vr + EPSV);
                float bbv = bet - mn * inv;
                const float* xr = e4 + (size_t)b * e4Stride + (size_t)grow * ldc + gcol;
                f32x4 x0 = *(const f32x4*)xr;
                f32x4 x1 = *(const f32x4*)(xr + 4);
                f32x4 o0, o1;
#pragma unroll
                for (int c = 0; c < 4; ++c) {
                    o0[c] = fmaxf(vf[c] * inv + bbv + x0[c], 0.f);
                    o1[c] = fmaxf(vf[c + 4] * inv + bbv + x1[c], 0.f);
                }
                float* Cf = (float*)C + (size_t)b * cStride + (size_t)grow * ldc + gcol;
                *(f32x4*)Cf = o0;
                *(f32x4*)(Cf + 4) = o1;
            }
        }
    }
}

// ---------------- flash attention (no-max softmax, swizzled LDS) ----------------
// qkt: [n][hw][1024] (q at h*128, k at 512+h*128); vt: [n][h][dv][hw]
__global__ __launch_bounds__(256, 2)
void attn_kernel(const bf16_t* __restrict__ qkt, const bf16_t* __restrict__ vt,
                 bf16_t* __restrict__ attn) {
    __shared__ bf16_t Ks[64 * 128];
    __shared__ bf16_t Vs[128 * 64];
    __shared__ bf16_t Ps[4 * 32 * 64];
    const int lane = threadIdx.x & 63;
    const int wave = threadIdx.x >> 6;
    const int qb = blockIdx.x, h = blockIdx.y, n = blockIdx.z;
    const int lrow = lane & 15, quad = lane >> 4;
    const int q0 = qb * 128 + wave * 32;

    bf16x8 qf[2][4];
#pragma unroll
    for (int rt = 0; rt < 2; ++rt)
#pragma unroll
        for (int kf = 0; kf < 4; ++kf)
            qf[rt][kf] = *(const bf16x8*)(qkt + (size_t)(n * HWD + q0 + rt * 16 + lrow) * QKLD
                                          + h * 128 + kf * 32 + quad * 8);

    f32x4 o[2][8];
    const f32x4 z4 = {0.f, 0.f, 0.f, 0.f};
#pragma unroll
    for (int rt = 0; rt < 2; ++rt)
#pragma unroll
        for (int d = 0; d < 8; ++d) o[rt][d] = z4;
    float l[2][4];
#pragma unroll
    for (int rt = 0; rt < 2; ++rt)
#pragma unroll
        for (int r = 0; r < 4; ++r) l[rt][r] = 0.f;

    const bf16_t* kbase = qkt + (size_t)n * HWD * QKLD + 512 + h * 128;
    const bf16_t* vbase = vt + (size_t)((n * 4 + h) * 128) * HWD;

    for (int kc = 0; kc < 16; ++kc) {
        __syncthreads();
#pragma unroll
        for (int j = 0; j < 4; ++j) {
            const int g = wave * 4 + j;
            const int krow = g * 4 + quad;
            const int kgl = lrow ^ (krow & 15);
            gl_lds16(kbase + (size_t)(kc * 64 + krow) * QKLD + kgl * 8,
                     (char*)Ks + g * 1024 + lane * 16);
            const int vrow = g * 8 + (lane >> 3);
            const int vgl = (lane & 7) ^ (vrow & 7);
            gl_lds16(vbase + (size_t)vrow * HWD + kc * 64 + vgl * 8,
                     (char*)Vs + g * 1024 + lane * 16);
        }
        __syncthreads();

        f32x4 s[2][4];
#pragma unroll
        for (int rt = 0; rt < 2; ++rt)
#pragma unroll
            for (int ct = 0; ct < 4; ++ct) s[rt][ct] = z4;
#pragma unroll
        for (int kf = 0; kf < 4; ++kf) {
#pragma unroll
            for (int ct = 0; ct < 4; ++ct) {
                bf16x8 kfrag = *(const bf16x8*)(Ks + (ct * 16 + lrow) * 128
                                                + ((kf * 4 + quad) ^ lrow) * 8);
                s[0][ct] = mfma16(qf[0][kf], kfrag, s[0][ct]);
                s[1][ct] = mfma16(qf[1][kf], kfrag, s[1][ct]);
            }
        }

#pragma unroll
        for (int rt = 0; rt < 2; ++rt) {
#pragma unroll
            for (int r = 0; r < 4; ++r) {
                const int prow = rt * 16 + quad * 4 + r;
                float rs = 0.f;
#pragma unroll
                for (int ct = 0; ct < 4; ++ct) {
                    float p = __expf(s[rt][ct][r]);
                    rs += p;
                    const int pg = (ct * 2 + (lrow >> 3)) ^ (prow & 7);
                    Ps[wave * 2048 + prow * 64 + pg * 8 + (lrow & 7)] = (bf16_t)p;
                }
                l[rt][r] += rs;
            }
        }
        asm volatile("s_waitcnt lgkmcnt(0)" ::: "memory");

#pragma unroll
        for (int kf = 0; kf < 2; ++kf) {
            bf16x8 pa0 = *(const bf16x8*)(Ps + wave * 2048 + lrow * 64
                                          + ((kf * 4 + quad) ^ (lrow & 7)) * 8);
            bf16x8 pa1 = *(const bf16x8*)(Ps + wave * 2048 + (16 + lrow) * 64
                                          + ((kf * 4 + quad) ^ (lrow & 7)) * 8);
#pragma unroll
            for (int d = 0; d < 8; ++d) {
                bf16x8 vf = *(const bf16x8*)(Vs + (d * 16 + lrow) * 64
                                             + ((kf * 4 + quad) ^ (lrow & 7)) * 8);
                o[0][d] = mfma16(pa0, vf, o[0][d]);
                o[1][d] = mfma16(pa1, vf, o[1][d]);
            }
        }
    }

#pragma unroll
    for (int rt = 0; rt < 2; ++rt)
#pragma unroll
        for (int r = 0; r < 4; ++r) {
#pragma unroll
            for (int off = 1; off < 16; off <<= 1)
                l[rt][r] += __shfl_xor(l[rt][r], off, 64);
        }

#pragma unroll
    for (int rt = 0; rt < 2; ++rt) {
#pragma unroll
        for (int r = 0; r < 4; ++r) {
            float linv = 1.f / l[rt][r];
            const size_t row = (size_t)n * HWD + q0 + rt * 16 + quad * 4 + r;
#pragma unroll
            for (int d = 0; d < 8; ++d) {
                float v = o[rt][d][r] * linv;
                v = fmaxf(v, 0.f);
                attn[row * MID + h * 128 + d * 16 + lrow] = (bf16_t)v;
            }
        }
    }
}

extern "C" void kernel_launch(void* const* d_in, const int* in_sizes, int n_in,
                              void* d_out, int out_size, void* d_ws, size_t ws_size,
                              hipStream_t stream) {
    const float* x       = (const float*)d_in[0];
    const float* conv1_w = (const float*)d_in[1];
    const float* gamma1  = (const float*)d_in[2];
    const float* beta1   = (const float*)d_in[3];
    const float* mean1   = (const float*)d_in[4];
    const float* var1    = (const float*)d_in[5];
    const float* qk_w    = (const float*)d_in[6];
    const float* v_w     = (const float*)d_in[7];
    const float* pos_h   = (const float*)d_in[8];
    const float* pos_w   = (const float*)d_in[9];
    const float* conv3_w = (const float*)d_in[10];
    const float* gamma3  = (const float*)d_in[11];
    const float* beta3   = (const float*)d_in[12];
    const float* mean3   = (const float*)d_in[13];
    const float* var3    = (const float*)d_in[14];
    float* out = (float*)d_out;

    char* ws = (char*)d_ws;
    size_t off = 0;
    auto carve = [&](size_t bytes) {
        void* p = ws + off;
        off += (bytes + 255) & ~(size_t)255;
        return p;
    };
    bf16_t* Xt    = (bf16_t*)carve((size_t)NB * HWD * CIN * 2);   // 64 MiB
    bf16_t* C1t   = (bf16_t*)carve((size_t)NB * HWD * MID * 2);   // 16 MiB
    bf16_t* QKt   = (bf16_t*)carve((size_t)NB * HWD * QKLD * 2);  // 32 MiB
    bf16_t* Vt    = (bf16_t*)carve((size_t)NB * 512 * HWD * 2);   // 16 MiB
    bf16_t* AttnT = (bf16_t*)carve((size_t)NB * HWD * MID * 2);   // 16 MiB
    bf16_t* W1b   = (bf16_t*)carve((size_t)512 * 2048 * 2);
    bf16_t* Wqkb  = (bf16_t*)carve((size_t)1024 * 512 * 2);
    bf16_t* Wvb   = (bf16_t*)carve((size_t)512 * 512 * 2);
    bf16_t* W3b   = (bf16_t*)carve((size_t)2048 * 512 * 2);
    float*  Emb   = (float*)carve((size_t)1024 * 128 * 4);

    prep_kernel<<<2048, 256, 0, stream>>>(conv1_w, qk_w, v_w, pos_h, pos_w, conv3_w,
                                          W1b, Wqkb, Wvb, W3b, Emb);

    transpose_x_kernel<<<dim3(64, 16, NB), 256, 0, stream>>>(x, Xt);

    // conv1 + BN + ReLU:  C1t[hw][512]   (BM=128 control)
    gemm_bt<1, 128><<<dim3(4, 8, NB), 256, 0, stream>>>(
        Xt, (long long)HWD * CIN, W1b, 0, CIN, MID,
        gamma1, beta1, mean1, var1, nullptr, 0, C1t, (long long)HWD * MID);

    // qk projection (+emb on k):  QKt[hw][1024]   (BM=256)
    gemm_bt<2, 256><<<dim3(8, 4, NB), 256, 0, stream>>>(
        C1t, (long long)HWD * MID, Wqkb, 0, MID, QKLD,
        nullptr, nullptr, nullptr, nullptr, Emb, 0, QKt, (long long)HWD * QKLD);

    // v projection, directly transposed:  Vt[h*128+dv][hw]   (BM=128 control)
    gemm_bt<4, 128><<<dim3(8, 4, NB), 256, 0, stream>>>(
        Wvb, 0, C1t, (long long)HWD * MID, MID, HWD,
        nullptr, nullptr, nullptr, nullptr, nullptr, 0, Vt, (long long)512 * HWD);

    attn_kernel<<<dim3(8, 4, NB), 256, 0, stream>>>(QKt, Vt, AttnT);

    // conv3 + BN + residual + ReLU -> out[co][hw] fp32   (BM=256)
    gemm_bt<3, 256><<<dim3(8, 8, NB), 256, 0, stream>>>(
        W3b, 0, AttnT, (long long)HWD * MID, MID, HWD,
        gamma3, beta3, mean3, var3, x, (long long)CIN * HWD, out, (long long)CIN * HWD);
}

// Round 8
// 480.914 us; speedup vs baseline: 1.0091x; 1.0091x over previous
//
#include <hip/hip_runtime.h>
#include <stdint.h>

typedef __bf16 bf16_t;
typedef __bf16 bf16x8 __attribute__((ext_vector_type(8)));
typedef float f32x4 __attribute__((ext_vector_type(4)));

#define EPSV 1e-5f
#define QSCALE 0.08838834764831845f
#define NB 16
#define HWD 1024
#define CIN 2048
#define MID 512
#define QKLD 1024

__device__ __forceinline__ void gl_lds16(const bf16_t* g, void* l) {
    __builtin_amdgcn_global_load_lds(
        (const __attribute__((address_space(1))) uint32_t*)g,
        (__attribute__((address_space(3))) uint32_t*)l, 16, 0, 0);
}

__device__ __forceinline__ f32x4 mfma16(bf16x8 a, bf16x8 b, f32x4 c) {
    return __builtin_amdgcn_mfma_f32_16x16x32_bf16(a, b, c, 0, 0, 0);
}

// ---------------- prep: weight casts + emb table ----------------
#define PW1 (512*2048)
#define PQK (PW1 + 1024*512)
#define PV  (PQK + 512*512)
#define PW3 (PV  + 2048*512)
#define PE  (PW3 + 1024*128)

__global__ void prep_kernel(const float* __restrict__ conv1_w,
                            const float* __restrict__ qk_w,
                            const float* __restrict__ v_w,
                            const float* __restrict__ pos_h,
                            const float* __restrict__ pos_w,
                            const float* __restrict__ conv3_w,
                            bf16_t* __restrict__ w1b, bf16_t* __restrict__ wqkb,
                            bf16_t* __restrict__ wvb, bf16_t* __restrict__ w3b,
                            float* __restrict__ emb) {
    int stride = gridDim.x * blockDim.x;
    for (int i = blockIdx.x * blockDim.x + threadIdx.x; i < PE; i += stride) {
        if (i < PW1) {
            w1b[i] = (bf16_t)conv1_w[i];
        } else if (i < PQK) {
            int j = i - PW1;
            int row = j >> 9;
            float v = (row < 512) ? qk_w[j] * QSCALE : qk_w[j];
            wqkb[j] = (bf16_t)v;
        } else if (i < PV) {
            int j = i - PQK;
            wvb[j] = (bf16_t)v_w[j];
        } else if (i < PW3) {
            int j = i - PV;
            w3b[j] = (bf16_t)conv3_w[j];
        } else {
            int j = i - PW3;
            int y = j >> 7, d = j & 127;
            emb[j] = pos_h[(y >> 5) * 128 + d] + pos_w[(y & 31) * 128 + d];
        }
    }
}

// ---------------- fused conv1: on-the-fly transpose+cast of x ----------------
// C1t[b][hw][512] = BN(ReLU)(X^T W1^T).
// A[m=hw][k=c] comes straight from x[b][c][hw] f32: per K-step each thread
// loads 8 coalesced float4 (8 c-rows x 4 hw), converts, ds_write_b128's one
// 8-c granule per hw row. Swizzle h(ar)=((ar>>2)^ar)&7 (instead of ar&7):
// write lanes (ar stride 4) AND fragment-read lanes (ar stride 1) both
// spread 8 lanes/bank-quad -> balanced, no serialization. Saves the
// transpose_x kernel + Xt round-trip (~192 MB HBM, one dispatch); x is
// L3-resident (128 MB < 256 MB LLC) so re-reads across grid.x hit LLC.
__global__ __launch_bounds__(256, 2)
void gemm1_fused(const float* __restrict__ x,
                 const bf16_t* __restrict__ B,   // W1b [512][2048] K-contig
                 const float* __restrict__ e0, const float* __restrict__ e1,
                 const float* __restrict__ e2, const float* __restrict__ e3,
                 bf16_t* __restrict__ C) {       // C1t [n][hw][512]
    __shared__ char smem[32768];
    bf16_t* As = (bf16_t*)smem;              // [128 hw][64 c], h()-swizzled
    bf16_t* Bs = (bf16_t*)(smem + 16384);    // [128 n][64 c], (row&7)-swizzled
    const int t = threadIdx.x;
    const int lane = t & 63;
    const int wave = t >> 6;
    const int tN = blockIdx.x * 128, tM = blockIdx.y * 128;
    const int b = blockIdx.z;

    const int wm = (wave >> 1) * 64, wn = (wave & 1) * 64;
    const int lrow = lane & 15, quad = lane >> 4;
    const int srow = lane >> 3;
    const int sgr = lane & 7;
    const int lg = sgr ^ srow;               // B-side source granule

    const int gc = (t >> 5) & 7;             // A: c-granule 0..7
    const int hwq = (t & 31) * 4;            // A: hw base 0..124

    f32x4 acc[4][4];
    const f32x4 z4 = {0.f, 0.f, 0.f, 0.f};
#pragma unroll
    for (int i = 0; i < 4; ++i)
#pragma unroll
        for (int j = 0; j < 4; ++j) acc[i][j] = z4;

    const float* xb = x + (size_t)b * CIN * HWD + tM + hwq;

    for (int k0 = 0; k0 < CIN; k0 += 64) {
        __syncthreads();
        // B tile via global_load_lds (lane-linear dest, pre-swizzled src)
#pragma unroll
        for (int j = 0; j < 4; ++j) {
            const int blk = wave * 4 + j;
            const int row = blk * 8 + srow;
            gl_lds16(B + (size_t)(tN + row) * CIN + k0 + lg * 8,
                     (char*)Bs + blk * 1024 + lane * 16);
        }
        // A tile: load f32, cast, transposed swizzled ds_write
        f32x4 xa[8];
        const float* xp = xb + (size_t)(k0 + gc * 8) * HWD;
#pragma unroll
        for (int i = 0; i < 8; ++i) xa[i] = *(const f32x4*)(xp + (size_t)i * HWD);
#pragma unroll
        for (int j = 0; j < 4; ++j) {
            const int ar = hwq + j;
            const int pg = gc ^ (((ar >> 2) ^ ar) & 7);
            bf16x8 g;
#pragma unroll
            for (int i = 0; i < 8; ++i) g[i] = (bf16_t)xa[i][j];
            *(bf16x8*)(As + ar * 64 + pg * 8) = g;
        }
        __syncthreads();   // drains vmcnt + lgkmcnt
#pragma unroll
        for (int kh = 0; kh < 2; ++kh) {
            bf16x8 af[4], bfr[4];
#pragma unroll
            for (int t4 = 0; t4 < 4; ++t4) {
                const int ar = wm + t4 * 16 + lrow;
                const int pga = (kh * 4 + quad) ^ (((ar >> 2) ^ ar) & 7);
                af[t4] = *(const bf16x8*)(As + ar * 64 + pga * 8);
                const int br = wn + t4 * 16 + lrow;
                bfr[t4] = *(const bf16x8*)(Bs + br * 64 + (((kh * 4 + quad) ^ (br & 7)) * 8));
            }
#pragma unroll
            for (int i = 0; i < 4; ++i)
#pragma unroll
                for (int j = 0; j < 4; ++j)
                    acc[i][j] = mfma16(af[i], bfr[j], acc[i][j]);
        }
    }

    // LDS-transposed epilogue: BN+ReLU by col -> bf16, coalesced 16B stores
    __syncthreads();
    float* Es = (float*)(smem + wave * 4352);
    const int pr = lane >> 3;
    const int pc = (lane & 7) * 8;
    const int gcol = tN + wn + pc;

#pragma unroll
    for (int i = 0; i < 4; ++i) {
#pragma unroll
        for (int j = 0; j < 4; ++j)
#pragma unroll
            for (int r = 0; r < 4; ++r)
                Es[(quad * 4 + r) * 68 + j * 16 + lrow] = acc[i][j][r];
#pragma unroll
        for (int p = 0; p < 2; ++p) {
            const int lr = p * 8 + pr;
            const int grow = tM + wm + i * 16 + lr;
            float vf[8];
            *(f32x4*)&vf[0] = *(const f32x4*)&Es[lr * 68 + pc];
            *(f32x4*)&vf[4] = *(const f32x4*)&Es[lr * 68 + pc + 4];
            float gg[8], bt[8], mm[8], vv[8];
            *(f32x4*)&gg[0] = *(const f32x4*)(e0 + gcol);
            *(f32x4*)&gg[4] = *(const f32x4*)(e0 + gcol + 4);
            *(f32x4*)&bt[0] = *(const f32x4*)(e1 + gcol);
            *(f32x4*)&bt[4] = *(const f32x4*)(e1 + gcol + 4);
            *(f32x4*)&mm[0] = *(const f32x4*)(e2 + gcol);
            *(f32x4*)&mm[4] = *(const f32x4*)(e2 + gcol + 4);
            *(f32x4*)&vv[0] = *(const f32x4*)(e3 + gcol);
            *(f32x4*)&vv[4] = *(const f32x4*)(e3 + gcol + 4);
            bf16x8 ob;
#pragma unroll
            for (int c = 0; c < 8; ++c) {
                float inv = gg[c] * rsqrtf(vv[c] + EPSV);
                float val = fmaxf(vf[c] * inv + (bt[c] - mm[c] * inv), 0.f);
                ob[c] = (bf16_t)val;
            }
            *(bf16x8*)(C + (size_t)b * HWD * MID + (size_t)grow * MID + gcol) = ob;
        }
    }
}

// ---------------- generic 128x128 bf16 gemm_bt, BK=64, swizzled LDS ----------------
// R1-proven structure (single-buffer, 2-barrier, (256,3)): dbuf/vmcnt (R5)
// and BM=256 (R6) both measured null-to-worse; this is the best-known config.
// C[m][n] = sum_k A[m][k]*B[n][k]; A:[M][K], B:[N][K] K-contiguous bf16.
// LDS tiles 128x64, rows 8 granules of 16B, phys_gran = gran ^ (row&7)
// (swizzle applied on the global source address; dest is lane-linear).
// Epilogue: LDS-transposed -> coalesced 16B stores + vectorized params.
// EPI 2: +emb for cols>=512 -> bf16 (ldc)
// EPI 3: BN by row + residual e4 + ReLU -> f32 (ldc)
// EPI 4: plain bf16 (ldc)
template <int EPI>
__global__ __launch_bounds__(256, 3)
void gemm_bt(const bf16_t* __restrict__ A, long long aStride,
             const bf16_t* __restrict__ B, long long bStride,
             int K, int ldc,
             const float* __restrict__ e0, const float* __restrict__ e1,
             const float* __restrict__ e2, const float* __restrict__ e3,
             const float* __restrict__ e4, long long e4Stride,
             void* __restrict__ C, long long cStride) {
    __shared__ f32x4 smemv[2048];               // 32 KiB, reused by epilogue
    char* smem = (char*)smemv;
    bf16_t* As = (bf16_t*)smem;
    bf16_t* Bs = (bf16_t*)(smem + 16384);
    const int lane = threadIdx.x & 63;
    const int wave = threadIdx.x >> 6;
    const int tN = blockIdx.x * 128, tM = blockIdx.y * 128;
    const int b = blockIdx.z;
    A += (size_t)b * aStride;
    B += (size_t)b * bStride;

    const int wm = (wave >> 1) * 64, wn = (wave & 1) * 64;
    const int lrow = lane & 15, quad = lane >> 4;
    const int srow = lane >> 3;          // 0..7 row within 8-row group
    const int sgr = lane & 7;            // phys granule (lane-linear dest)
    const int lg = sgr ^ srow;           // logical granule at source

    f32x4 acc[4][4];
    const f32x4 z4 = {0.f, 0.f, 0.f, 0.f};
#pragma unroll
    for (int i = 0; i < 4; ++i)
#pragma unroll
        for (int j = 0; j < 4; ++j) acc[i][j] = z4;

    for (int k0 = 0; k0 < K; k0 += 64) {
        __syncthreads();
#pragma unroll
        for (int j = 0; j < 4; ++j) {
            const int blk = wave * 4 + j;        // 0..15 (8 rows each)
            const int row = blk * 8 + srow;
            gl_lds16(A + (size_t)(tM + row) * K + k0 + lg * 8,
                     (char*)As + blk * 1024 + lane * 16);
            gl_lds16(B + (size_t)(tN + row) * K + k0 + lg * 8,
                     (char*)Bs + blk * 1024 + lane * 16);
        }
        __syncthreads();
#pragma unroll
        for (int kh = 0; kh < 2; ++kh) {
            bf16x8 af[4], bfr[4];
#pragma unroll
            for (int t = 0; t < 4; ++t) {
                const int ar = wm + t * 16 + lrow;
                af[t] = *(const bf16x8*)(As + ar * 64 + (((kh * 4 + quad) ^ (ar & 7)) * 8));
                const int br = wn + t * 16 + lrow;
                bfr[t] = *(const bf16x8*)(Bs + br * 64 + (((kh * 4 + quad) ^ (br & 7)) * 8));
            }
#pragma unroll
            for (int i = 0; i < 4; ++i)
#pragma unroll
                for (int j = 0; j < 4; ++j)
                    acc[i][j] = mfma16(af[i], bfr[j], acc[i][j]);
        }
    }

    // ---------------- LDS-transposed epilogue ----------------
    __syncthreads();                       // other waves done reading As/Bs
    float* Es = (float*)(smem + wave * 4352);   // 16*68*4 = 4352 B per wave
    const int pr = lane >> 3;              // 0..7  row within pass
    const int pc = (lane & 7) * 8;         // col8 base
    const int gcol = tN + wn + pc;

#pragma unroll
    for (int i = 0; i < 4; ++i) {
#pragma unroll
        for (int j = 0; j < 4; ++j)
#pragma unroll
            for (int r = 0; r < 4; ++r)
                Es[(quad * 4 + r) * 68 + j * 16 + lrow] = acc[i][j][r];
        // wave-synchronous: compiler orders ds_write -> ds_read via lgkmcnt
#pragma unroll
        for (int p = 0; p < 2; ++p) {
            const int lr = p * 8 + pr;
            const int grow = tM + wm + i * 16 + lr;
            float vf[8];
            *(f32x4*)&vf[0] = *(const f32x4*)&Es[lr * 68 + pc];
            *(f32x4*)&vf[4] = *(const f32x4*)&Es[lr * 68 + pc + 4];

            if constexpr (EPI == 2) {
                bf16x8 ob;
                if (gcol >= 512) {            // wave-uniform
                    float ev[8];
                    const float* ep = e4 + (size_t)grow * 128 + (gcol & 127);
                    *(f32x4*)&ev[0] = *(const f32x4*)ep;
                    *(f32x4*)&ev[4] = *(const f32x4*)(ep + 4);
#pragma unroll
                    for (int c = 0; c < 8; ++c) ob[c] = (bf16_t)(vf[c] + ev[c]);
                } else {
#pragma unroll
                    for (int c = 0; c < 8; ++c) ob[c] = (bf16_t)vf[c];
                }
                bf16_t* Cb = (bf16_t*)C + (size_t)b * cStride;
                *(bf16x8*)(Cb + (size_t)grow * ldc + gcol) = ob;
            } else if constexpr (EPI == 4) {
                bf16x8 ob;
#pragma unroll
                for (int c = 0; c < 8; ++c) ob[c] = (bf16_t)vf[c];
                bf16_t* Cb = (bf16_t*)C + (size_t)b * cStride;
                *(bf16x8*)(Cb + (size_t)grow * ldc + gcol) = ob;
            } else {                          // EPI 3
                float g = e0[grow], bet = e1[grow], mn = e2[grow], vr = e3[grow];
                float inv = g * rsqrtf(vr + EPSV);
                float bbv = bet - mn * inv;
                const float* xr = e4 + (size_t)b * e4Stride + (size_t)grow * ldc + gcol;
                f32x4 x0 = *(const f32x4*)xr;
                f32x4 x1 = *(const f32x4*)(xr + 4);
                f32x4 o0, o1;
#pragma unroll
                for (int c = 0; c < 4; ++c) {
                    o0[c] = fmaxf(vf[c] * inv + bbv + x0[c], 0.f);
                    o1[c] = fmaxf(vf[c + 4] * inv + bbv + x1[c], 0.f);
                }
                float* Cf = (float*)C + (size_t)b * cStride + (size_t)grow * ldc + gcol;
                *(f32x4*)Cf = o0;
                *(f32x4*)(Cf + 4) = o1;
            }
        }
    }
}

// ---------------- flash attention (no-max softmax, swizzled LDS) ----------------
// qkt: [n][hw][1024] (q at h*128, k at 512+h*128); vt: [n][h][dv][hw]
__global__ __launch_bounds__(256, 2)
void attn_kernel(const bf16_t* __restrict__ qkt, const bf16_t* __restrict__ vt,
                 bf16_t* __restrict__ attn) {
    __shared__ bf16_t Ks[64 * 128];
    __shared__ bf16_t Vs[128 * 64];
    __shared__ bf16_t Ps[4 * 32 * 64];
    const int lane = threadIdx.x & 63;
    const int wave = threadIdx.x >> 6;
    const int qb = blockIdx.x, h = blockIdx.y, n = blockIdx.z;
    const int lrow = lane & 15, quad = lane >> 4;
    const int q0 = qb * 128 + wave * 32;

    bf16x8 qf[2][4];
#pragma unroll
    for (int rt = 0; rt < 2; ++rt)
#pragma unroll
        for (int kf = 0; kf < 4; ++kf)
            qf[rt][kf] = *(const bf16x8*)(qkt + (size_t)(n * HWD + q0 + rt * 16 + lrow) * QKLD
                                          + h * 128 + kf * 32 + quad * 8);

    f32x4 o[2][8];
    const f32x4 z4 = {0.f, 0.f, 0.f, 0.f};
#pragma unroll
    for (int rt = 0; rt < 2; ++rt)
#pragma unroll
        for (int d = 0; d < 8; ++d) o[rt][d] = z4;
    float l[2][4];
#pragma unroll
    for (int rt = 0; rt < 2; ++rt)
#pragma unroll
        for (int r = 0; r < 4; ++r) l[rt][r] = 0.f;

    const bf16_t* kbase = qkt + (size_t)n * HWD * QKLD + 512 + h * 128;
    const bf16_t* vbase = vt + (size_t)((n * 4 + h) * 128) * HWD;

    for (int kc = 0; kc < 16; ++kc) {
        __syncthreads();
#pragma unroll
        for (int j = 0; j < 4; ++j) {
            const int g = wave * 4 + j;
            const int krow = g * 4 + quad;
            const int kgl = lrow ^ (krow & 15);
            gl_lds16(kbase + (size_t)(kc * 64 + krow) * QKLD + kgl * 8,
                     (char*)Ks + g * 1024 + lane * 16);
            const int vrow = g * 8 + (lane >> 3);
            const int vgl = (lane & 7) ^ (vrow & 7);
            gl_lds16(vbase + (size_t)vrow * HWD + kc * 64 + vgl * 8,
                     (char*)Vs + g * 1024 + lane * 16);
        }
        __syncthreads();

        f32x4 s[2][4];
#pragma unroll
        for (int rt = 0; rt < 2; ++rt)
#pragma unroll
            for (int ct = 0; ct < 4; ++ct) s[rt][ct] = z4;
#pragma unroll
        for (int kf = 0; kf < 4; ++kf) {
#pragma unroll
            for (int ct = 0; ct < 4; ++ct) {
                bf16x8 kfrag = *(const bf16x8*)(Ks + (ct * 16 + lrow) * 128
                                                + ((kf * 4 + quad) ^ lrow) * 8);
                s[0][ct] = mfma16(qf[0][kf], kfrag, s[0][ct]);
                s[1][ct] = mfma16(qf[1][kf], kfrag, s[1][ct]);
            }
        }

#pragma unroll
        for (int rt = 0; rt < 2; ++rt) {
#pragma unroll
            for (int r = 0; r < 4; ++r) {
                const int prow = rt * 16 + quad * 4 + r;
                float rs = 0.f;
#pragma unroll
                for (int ct = 0; ct < 4; ++ct) {
                    float p = __expf(s[rt][ct][r]);
                    rs += p;
                    const int pg = (ct * 2 + (lrow >> 3)) ^ (prow & 7);
                    Ps[wave * 2048 + prow * 64 + pg * 8 + (lrow & 7)] = (bf16_t)p;
                }
                l[rt][r] += rs;
            }
        }
        asm volatile("s_waitcnt lgkmcnt(0)" ::: "memory");

#pragma unroll
        for (int kf = 0; kf < 2; ++kf) {
            bf16x8 pa0 = *(const bf16x8*)(Ps + wave * 2048 + lrow * 64
                                          + ((kf * 4 + quad) ^ (lrow & 7)) * 8);
            bf16x8 pa1 = *(const bf16x8*)(Ps + wave * 2048 + (16 + lrow) * 64
                                          + ((kf * 4 + quad) ^ (lrow & 7)) * 8);
#pragma unroll
            for (int d = 0; d < 8; ++d) {
                bf16x8 vf = *(const bf16x8*)(Vs + (d * 16 + lrow) * 64
                                             + ((kf * 4 + quad) ^ (lrow & 7)) * 8);
                o[0][d] = mfma16(pa0, vf, o[0][d]);
                o[1][d] = mfma16(pa1, vf, o[1][d]);
            }
        }
    }

#pragma unroll
    for (int rt = 0; rt < 2; ++rt)
#pragma unroll
        for (int r = 0; r < 4; ++r) {
#pragma unroll
            for (int off = 1; off < 16; off <<= 1)
                l[rt][r] += __shfl_xor(l[rt][r], off, 64);
        }

#pragma unroll
    for (int rt = 0; rt < 2; ++rt) {
#pragma unroll
        for (int r = 0; r < 4; ++r) {
            float linv = 1.f / l[rt][r];
            const size_t row = (size_t)n * HWD + q0 + rt * 16 + quad * 4 + r;
#pragma unroll
            for (int d = 0; d < 8; ++d) {
                float v = o[rt][d][r] * linv;
                v = fmaxf(v, 0.f);
                attn[row * MID + h * 128 + d * 16 + lrow] = (bf16_t)v;
            }
        }
    }
}

extern "C" void kernel_launch(void* const* d_in, const int* in_sizes, int n_in,
                              void* d_out, int out_size, void* d_ws, size_t ws_size,
                              hipStream_t stream) {
    const float* x       = (const float*)d_in[0];
    const float* conv1_w = (const float*)d_in[1];
    const float* gamma1  = (const float*)d_in[2];
    const float* beta1   = (const float*)d_in[3];
    const float* mean1   = (const float*)d_in[4];
    const float* var1    = (const float*)d_in[5];
    const float* qk_w    = (const float*)d_in[6];
    const float* v_w     = (const float*)d_in[7];
    const float* pos_h   = (const float*)d_in[8];
    const float* pos_w   = (const float*)d_in[9];
    const float* conv3_w = (const float*)d_in[10];
    const float* gamma3  = (const float*)d_in[11];
    const float* beta3   = (const float*)d_in[12];
    const float* mean3   = (const float*)d_in[13];
    const float* var3    = (const float*)d_in[14];
    float* out = (float*)d_out;

    char* ws = (char*)d_ws;
    size_t off = 0;
    auto carve = [&](size_t bytes) {
        void* p = ws + off;
        off += (bytes + 255) & ~(size_t)255;
        return p;
    };
    bf16_t* C1t   = (bf16_t*)carve((size_t)NB * HWD * MID * 2);   // 16 MiB
    bf16_t* QKt   = (bf16_t*)carve((size_t)NB * HWD * QKLD * 2);  // 32 MiB
    bf16_t* Vt    = (bf16_t*)carve((size_t)NB * 512 * HWD * 2);   // 16 MiB
    bf16_t* AttnT = (bf16_t*)carve((size_t)NB * HWD * MID * 2);   // 16 MiB
    bf16_t* W1b   = (bf16_t*)carve((size_t)512 * 2048 * 2);
    bf16_t* Wqkb  = (bf16_t*)carve((size_t)1024 * 512 * 2);
    bf16_t* Wvb   = (bf16_t*)carve((size_t)512 * 512 * 2);
    bf16_t* W3b   = (bf16_t*)carve((size_t)2048 * 512 * 2);
    float*  Emb   = (float*)carve((size_t)1024 * 128 * 4);

    prep_kernel<<<2048, 256, 0, stream>>>(conv1_w, qk_w, v_w, pos_h, pos_w, conv3_w,
                                          W1b, Wqkb, Wvb, W3b, Emb);

    // conv1 + BN + ReLU, fused x-transpose:  C1t[hw][512]
    gemm1_fused<<<dim3(4, 8, NB), 256, 0, stream>>>(
        x, W1b, gamma1, beta1, mean1, var1, C1t);

    // qk projection (+emb on k):  QKt[hw][1024]
    gemm_bt<2><<<dim3(8, 8, NB), 256, 0, stream>>>(
        C1t, (long long)HWD * MID, Wqkb, 0, MID, QKLD,
        nullptr, nullptr, nullptr, nullptr, Emb, 0, QKt, (long long)HWD * QKLD);

    // v projection, directly transposed:  Vt[h*128+dv][hw]
    gemm_bt<4><<<dim3(8, 4, NB), 256, 0, stream>>>(
        Wvb, 0, C1t, (long long)HWD * MID, MID, HWD,
        nullptr, nullptr, nullptr, nullptr, nullptr, 0, Vt, (long long)512 * HWD);

    attn_kernel<<<dim3(8, 4, NB), 256, 0, stream>>>(QKt, Vt, AttnT);

    // conv3 + BN + residual + ReLU -> out[co][hw] fp32
    gemm_bt<3><<<dim3(8, 16, NB), 256, 0, stream>>>(
        W3b, 0, AttnT, (long long)HWD * MID, MID, HWD,
        gamma3, beta3, mean3, var3, x, (long long)CIN * HWD, out, (long long)CIN * HWD);
}

// Round 10
// 467.023 us; speedup vs baseline: 1.0391x; 1.0297x over previous
//
#include <hip/hip_runtime.h>
#include <stdint.h>

typedef __bf16 bf16_t;
typedef __bf16 bf16x8 __attribute__((ext_vector_type(8)));
typedef float f32x4 __attribute__((ext_vector_type(4)));

#define EPSV 1e-5f
#define QSCALE 0.08838834764831845f
#define NB 16
#define HWD 1024
#define CIN 2048
#define MID 512
#define QKLD 1024

__device__ __forceinline__ void gl_lds16(const bf16_t* g, void* l) {
    __builtin_amdgcn_global_load_lds(
        (const __attribute__((address_space(1))) uint32_t*)g,
        (__attribute__((address_space(3))) uint32_t*)l, 16, 0, 0);
}

__device__ __forceinline__ f32x4 mfma16(bf16x8 a, bf16x8 b, f32x4 c) {
    return __builtin_amdgcn_mfma_f32_16x16x32_bf16(a, b, c, 0, 0, 0);
}

// ---------------- prep: weight casts + emb table ----------------
#define PW1 (512*2048)
#define PQK (PW1 + 1024*512)
#define PV  (PQK + 512*512)
#define PW3 (PV  + 2048*512)
#define PE  (PW3 + 1024*128)

__global__ void prep_kernel(const float* __restrict__ conv1_w,
                            const float* __restrict__ qk_w,
                            const float* __restrict__ v_w,
                            const float* __restrict__ pos_h,
                            const float* __restrict__ pos_w,
                            const float* __restrict__ conv3_w,
                            bf16_t* __restrict__ w1b, bf16_t* __restrict__ wqkb,
                            bf16_t* __restrict__ wvb, bf16_t* __restrict__ w3b,
                            float* __restrict__ emb) {
    int stride = gridDim.x * blockDim.x;
    for (int i = blockIdx.x * blockDim.x + threadIdx.x; i < PE; i += stride) {
        if (i < PW1) {
            w1b[i] = (bf16_t)conv1_w[i];
        } else if (i < PQK) {
            int j = i - PW1;
            int row = j >> 9;
            float v = (row < 512) ? qk_w[j] * QSCALE : qk_w[j];
            wqkb[j] = (bf16_t)v;
        } else if (i < PV) {
            int j = i - PQK;
            wvb[j] = (bf16_t)v_w[j];
        } else if (i < PW3) {
            int j = i - PV;
            w3b[j] = (bf16_t)conv3_w[j];
        } else {
            int j = i - PW3;
            int y = j >> 7, d = j & 127;
            emb[j] = pos_h[(y >> 5) * 128 + d] + pos_w[(y & 31) * 128 + d];
        }
    }
}

// ---------------- transpose x: [n][c][hw] f32 -> [n][hw][c] bf16 ----------------
// Kept as a separate kernel: fusing it into gemm1 (R8) saved zero bytes
// (x re-read across the 4 N-tiles = the Xt round-trip) and lost the
// coalesced global_load_lds A-path (126us vs ~85us combined).
__global__ void transpose_x_kernel(const float* __restrict__ x, bf16_t* __restrict__ xt) {
    __shared__ uint32_t tileT[64][20];   // [hw][c-pair], pad 16->20
    const int n = blockIdx.z;
    const int c0 = blockIdx.x * 32;
    const int hw0 = blockIdx.y * 64;
    const int t = threadIdx.x;

    const int cp = t >> 4;            // 0..15 c-pair
    const int hw4 = (t & 15) * 4;     // 0..60
    const float* p0 = x + ((size_t)n * CIN + c0 + 2 * cp) * HWD + hw0 + hw4;
    const float4 a = *(const float4*)p0;
    const float4 b = *(const float4*)(p0 + HWD);
    float av[4] = {a.x, a.y, a.z, a.w};
    float bv[4] = {b.x, b.y, b.z, b.w};
#pragma unroll
    for (int i = 0; i < 4; ++i) {
        uint16_t lo = __builtin_bit_cast(uint16_t, (bf16_t)av[i]);
        uint16_t hi = __builtin_bit_cast(uint16_t, (bf16_t)bv[i]);
        tileT[hw4 + i][cp] = (uint32_t)lo | ((uint32_t)hi << 16);
    }
    __syncthreads();
    const int hw = t >> 2;            // 0..63
    const int seg = (t & 3) * 4;      // u32 seg
    uint4 v = *(const uint4*)&tileT[hw][seg];
    *(uint4*)(xt + ((size_t)n * HWD + hw0 + hw) * CIN + c0 + 2 * seg) = v;
}

// ---------------- generic 128x128 bf16 gemm body, BK=64, swizzled LDS ----------------
// R1-proven structure (single-buffer, 2-barrier): dbuf/vmcnt (R5), BM=256
// (R6), x-fusion (R8) all measured null-to-worse; this is best-known.
// C[m][n] = sum_k A[m][k]*B[n][k]; A:[M][K], B:[N][K] K-contiguous bf16.
// LDS tiles 128x64, rows 8 granules of 16B, phys_gran = gran ^ (row&7)
// (swizzle applied on the global source address; dest is lane-linear).
// Epilogue: LDS-transposed -> coalesced 16B stores + vectorized params.
// EPI 1: BN+ReLU by col -> bf16; EPI 2: +emb cols>=512 -> bf16;
// EPI 3: BN by row + residual e4 + ReLU -> f32; EPI 4: plain bf16.
template <int EPI>
__device__ __forceinline__
void gemm_body(const bf16_t* __restrict__ A, long long aStride,
               const bf16_t* __restrict__ B, long long bStride,
               int K, int ldc,
               const float* __restrict__ e0, const float* __restrict__ e1,
               const float* __restrict__ e2, const float* __restrict__ e3,
               const float* __restrict__ e4, long long e4Stride,
               void* __restrict__ C, long long cStride,
               int bx, int by, int b, char* smem) {
    bf16_t* As = (bf16_t*)smem;
    bf16_t* Bs = (bf16_t*)(smem + 16384);
    const int lane = threadIdx.x & 63;
    const int wave = threadIdx.x >> 6;
    const int tN = bx * 128, tM = by * 128;
    A += (size_t)b * aStride;
    B += (size_t)b * bStride;

    const int wm = (wave >> 1) * 64, wn = (wave & 1) * 64;
    const int lrow = lane & 15, quad = lane >> 4;
    const int srow = lane >> 3;          // 0..7 row within 8-row group
    const int sgr = lane & 7;            // phys granule (lane-linear dest)
    const int lg = sgr ^ srow;           // logical granule at source

    f32x4 acc[4][4];
    const f32x4 z4 = {0.f, 0.f, 0.f, 0.f};
#pragma unroll
    for (int i = 0; i < 4; ++i)
#pragma unroll
        for (int j = 0; j < 4; ++j) acc[i][j] = z4;

    for (int k0 = 0; k0 < K; k0 += 64) {
        __syncthreads();
#pragma unroll
        for (int j = 0; j < 4; ++j) {
            const int blk = wave * 4 + j;        // 0..15 (8 rows each)
            const int row = blk * 8 + srow;
            gl_lds16(A + (size_t)(tM + row) * K + k0 + lg * 8,
                     (char*)As + blk * 1024 + lane * 16);
            gl_lds16(B + (size_t)(tN + row) * K + k0 + lg * 8,
                     (char*)Bs + blk * 1024 + lane * 16);
        }
        __syncthreads();
#pragma unroll
        for (int kh = 0; kh < 2; ++kh) {
            bf16x8 af[4], bfr[4];
#pragma unroll
            for (int t = 0; t < 4; ++t) {
                const int ar = wm + t * 16 + lrow;
                af[t] = *(const bf16x8*)(As + ar * 64 + (((kh * 4 + quad) ^ (ar & 7)) * 8));
                const int br = wn + t * 16 + lrow;
                bfr[t] = *(const bf16x8*)(Bs + br * 64 + (((kh * 4 + quad) ^ (br & 7)) * 8));
            }
#pragma unroll
            for (int i = 0; i < 4; ++i)
#pragma unroll
                for (int j = 0; j < 4; ++j)
                    acc[i][j] = mfma16(af[i], bfr[j], acc[i][j]);
        }
    }

    // ---------------- LDS-transposed epilogue ----------------
    __syncthreads();                       // other waves done reading As/Bs
    float* Es = (float*)(smem + wave * 4352);   // 16*68*4 = 4352 B per wave
    const int pr = lane >> 3;              // 0..7  row within pass
    const int pc = (lane & 7) * 8;         // col8 base
    const int gcol = tN + wn + pc;

#pragma unroll
    for (int i = 0; i < 4; ++i) {
#pragma unroll
        for (int j = 0; j < 4; ++j)
#pragma unroll
            for (int r = 0; r < 4; ++r)
                Es[(quad * 4 + r) * 68 + j * 16 + lrow] = acc[i][j][r];
        // wave-synchronous: compiler orders ds_write -> ds_read via lgkmcnt
#pragma unroll
        for (int p = 0; p < 2; ++p) {
            const int lr = p * 8 + pr;
            const int grow = tM + wm + i * 16 + lr;
            float vf[8];
            *(f32x4*)&vf[0] = *(const f32x4*)&Es[lr * 68 + pc];
            *(f32x4*)&vf[4] = *(const f32x4*)&Es[lr * 68 + pc + 4];

            if constexpr (EPI == 1) {
                float gg[8], bt[8], mm[8], vv[8];
                *(f32x4*)&gg[0] = *(const f32x4*)(e0 + gcol);
                *(f32x4*)&gg[4] = *(const f32x4*)(e0 + gcol + 4);
                *(f32x4*)&bt[0] = *(const f32x4*)(e1 + gcol);
                *(f32x4*)&bt[4] = *(const f32x4*)(e1 + gcol + 4);
                *(f32x4*)&mm[0] = *(const f32x4*)(e2 + gcol);
                *(f32x4*)&mm[4] = *(const f32x4*)(e2 + gcol + 4);
                *(f32x4*)&vv[0] = *(const f32x4*)(e3 + gcol);
                *(f32x4*)&vv[4] = *(const f32x4*)(e3 + gcol + 4);
                bf16x8 ob;
#pragma unroll
                for (int c = 0; c < 8; ++c) {
                    float inv = gg[c] * rsqrtf(vv[c] + EPSV);
                    float val = fmaxf(vf[c] * inv + (bt[c] - mm[c] * inv), 0.f);
                    ob[c] = (bf16_t)val;
                }
                bf16_t* Cb = (bf16_t*)C + (size_t)b * cStride;
                *(bf16x8*)(Cb + (size_t)grow * ldc + gcol) = ob;
            } else if constexpr (EPI == 2) {
                bf16x8 ob;
                if (gcol >= 512) {            // wave-uniform
                    float ev[8];
                    const float* ep = e4 + (size_t)grow * 128 + (gcol & 127);
                    *(f32x4*)&ev[0] = *(const f32x4*)ep;
                    *(f32x4*)&ev[4] = *(const f32x4*)(ep + 4);
#pragma unroll
                    for (int c = 0; c < 8; ++c) ob[c] = (bf16_t)(vf[c] + ev[c]);
                } else {
#pragma unroll
                    for (int c = 0; c < 8; ++c) ob[c] = (bf16_t)vf[c];
                }
                bf16_t* Cb = (bf16_t*)C + (size_t)b * cStride;
                *(bf16x8*)(Cb + (size_t)grow * ldc + gcol) = ob;
            } else if constexpr (EPI == 4) {
                bf16x8 ob;
#pragma unroll
                for (int c = 0; c < 8; ++c) ob[c] = (bf16_t)vf[c];
                bf16_t* Cb = (bf16_t*)C + (size_t)b * cStride;
                *(bf16x8*)(Cb + (size_t)grow * ldc + gcol) = ob;
            } else {                          // EPI 3
                float g = e0[grow], bet = e1[grow], mn = e2[grow], vr = e3[grow];
                float inv = g * rsqrtf(vr + EPSV);
                float bbv = bet - mn * inv;
                const float* xr = e4 + (size_t)b * e4Stride + (size_t)grow * ldc + gcol;
                f32x4 x0 = *(const f32x4*)xr;
                f32x4 x1 = *(const f32x4*)(xr + 4);
                f32x4 o0, o1;
#pragma unroll
                for (int c = 0; c < 4; ++c) {
                    o0[c] = fmaxf(vf[c] * inv + bbv + x0[c], 0.f);
                    o1[c] = fmaxf(vf[c + 4] * inv + bbv + x1[c], 0.f);
                }
                float* Cf = (float*)C + (size_t)b * cStride + (size_t)grow * ldc + gcol;
                *(f32x4*)Cf = o0;
                *(f32x4*)(Cf + 4) = o1;
            }
        }
    }
}

template <int EPI>
__global__ __launch_bounds__(256, 3)
void gemm_bt(const bf16_t* __restrict__ A, long long aStride,
             const bf16_t* __restrict__ B, long long bStride,
             int K, int ldc,
             const float* __restrict__ e0, const float* __restrict__ e1,
             const float* __restrict__ e2, const float* __restrict__ e3,
             const float* __restrict__ e4, long long e4Stride,
             void* __restrict__ C, long long cStride) {
    __shared__ char smem[32768];
    gemm_body<EPI>(A, aStride, B, bStride, K, ldc, e0, e1, e2, e3, e4, e4Stride,
                   C, cStride, blockIdx.x, blockIdx.y, blockIdx.z, smem);
}

// Merged QK + V projection: one dispatch, grid (8, 12, NB).
// by<8 -> gemm2 tile (QKt, +emb epilogue); by>=8 -> gemmv tile (Vt, plain).
// Both K=512, ldc=1024, same inner loop -> union register pressure ~ either
// alone; wave-uniform branch. Kills one kernel boundary and packs gemmv's
// 512-block tail together with gemm2's 1024 blocks.
__global__ __launch_bounds__(256, 3)
void gemm_qkv(const bf16_t* __restrict__ C1t,
              const bf16_t* __restrict__ Wqkb,
              const bf16_t* __restrict__ Wvb,
              const float* __restrict__ Emb,
              bf16_t* __restrict__ QKt,
              bf16_t* __restrict__ Vt) {
    __shared__ char smem[32768];
    if (blockIdx.y < 8) {
        gemm_body<2>(C1t, (long long)HWD * MID, Wqkb, 0, MID, QKLD,
                     nullptr, nullptr, nullptr, nullptr, Emb, 0,
                     QKt, (long long)HWD * QKLD,
                     blockIdx.x, blockIdx.y, blockIdx.z, smem);
    } else {
        gemm_body<4>(Wvb, 0, C1t, (long long)HWD * MID, MID, HWD,
                     nullptr, nullptr, nullptr, nullptr, nullptr, 0,
                     Vt, (long long)512 * HWD,
                     blockIdx.x, blockIdx.y - 8, blockIdx.z, smem);
    }
}

// ---------------- flash attention (no-max softmax, swizzled LDS) ----------------
// qkt: [n][hw][1024] (q at h*128, k at 512+h*128); vt: [n][h][dv][hw]
__global__ __launch_bounds__(256, 2)
void attn_kernel(const bf16_t* __restrict__ qkt, const bf16_t* __restrict__ vt,
                 bf16_t* __restrict__ attn) {
    __shared__ bf16_t Ks[64 * 128];
    __shared__ bf16_t Vs[128 * 64];
    __shared__ bf16_t Ps[4 * 32 * 64];
    const int lane = threadIdx.x & 63;
    const int wave = threadIdx.x >> 6;
    const int qb = blockIdx.x, h = blockIdx.y, n = blockIdx.z;
    const int lrow = lane & 15, quad = lane >> 4;
    const int q0 = qb * 128 + wave * 32;

    bf16x8 qf[2][4];
#pragma unroll
    for (int rt = 0; rt < 2; ++rt)
#pragma unroll
        for (int kf = 0; kf < 4; ++kf)
            qf[rt][kf] = *(const bf16x8*)(qkt + (size_t)(n * HWD + q0 + rt * 16 + lrow) * QKLD
                                          + h * 128 + kf * 32 + quad * 8);

    f32x4 o[2][8];
    const f32x4 z4 = {0.f, 0.f, 0.f, 0.f};
#pragma unroll
    for (int rt = 0; rt < 2; ++rt)
#pragma unroll
        for (int d = 0; d < 8; ++d) o[rt][d] = z4;
    float l[2][4];
#pragma unroll
    for (int rt = 0; rt < 2; ++rt)
#pragma unroll
        for (int r = 0; r < 4; ++r) l[rt][r] = 0.f;

    const bf16_t* kbase = qkt + (size_t)n * HWD * QKLD + 512 + h * 128;
    const bf16_t* vbase = vt + (size_t)((n * 4 + h) * 128) * HWD;

    for (int kc = 0; kc < 16; ++kc) {
        __syncthreads();
#pragma unroll
        for (int j = 0; j < 4; ++j) {
            const int g = wave * 4 + j;
            const int krow = g * 4 + quad;
            const int kgl = lrow ^ (krow & 15);
            gl_lds16(kbase + (size_t)(kc * 64 + krow) * QKLD + kgl * 8,
                     (char*)Ks + g * 1024 + lane * 16);
            const int vrow = g * 8 + (lane >> 3);
            const int vgl = (lane & 7) ^ (vrow & 7);
            gl_lds16(vbase + (size_t)vrow * HWD + kc * 64 + vgl * 8,
                     (char*)Vs + g * 1024 + lane * 16);
        }
        __syncthreads();

        f32x4 s[2][4];
#pragma unroll
        for (int rt = 0; rt < 2; ++rt)
#pragma unroll
            for (int ct = 0; ct < 4; ++ct) s[rt][ct] = z4;
#pragma unroll
        for (int kf = 0; kf < 4; ++kf) {
#pragma unroll
            for (int ct = 0; ct < 4; ++ct) {
                bf16x8 kfrag = *(const bf16x8*)(Ks + (ct * 16 + lrow) * 128
                                                + ((kf * 4 + quad) ^ lrow) * 8);
                s[0][ct] = mfma16(qf[0][kf], kfrag, s[0][ct]);
                s[1][ct] = mfma16(qf[1][kf], kfrag, s[1][ct]);
            }
        }

#pragma unroll
        for (int rt = 0; rt < 2; ++rt) {
#pragma unroll
            for (int r = 0; r < 4; ++r) {
                const int prow = rt * 16 + quad * 4 + r;
                float rs = 0.f;
#pragma unroll
                for (int ct = 0; ct < 4; ++ct) {
                    float p = __expf(s[rt][ct][r]);
                    rs += p;
                    const int pg = (ct * 2 + (lrow >> 3)) ^ (prow & 7);
                    Ps[wave * 2048 + prow * 64 + pg * 8 + (lrow & 7)] = (bf16_t)p;
                }
                l[rt][r] += rs;
            }
        }
        asm volatile("s_waitcnt lgkmcnt(0)" ::: "memory");

#pragma unroll
        for (int kf = 0; kf < 2; ++kf) {
            bf16x8 pa0 = *(const bf16x8*)(Ps + wave * 2048 + lrow * 64
                                          + ((kf * 4 + quad) ^ (lrow & 7)) * 8);
            bf16x8 pa1 = *(const bf16x8*)(Ps + wave * 2048 + (16 + lrow) * 64
                                          + ((kf * 4 + quad) ^ (lrow & 7)) * 8);
#pragma unroll
            for (int d = 0; d < 8; ++d) {
                bf16x8 vf = *(const bf16x8*)(Vs + (d * 16 + lrow) * 64
                                             + ((kf * 4 + quad) ^ (lrow & 7)) * 8);
                o[0][d] = mfma16(pa0, vf, o[0][d]);
                o[1][d] = mfma16(pa1, vf, o[1][d]);
            }
        }
    }

#pragma unroll
    for (int rt = 0; rt < 2; ++rt)
#pragma unroll
        for (int r = 0; r < 4; ++r) {
#pragma unroll
            for (int off = 1; off < 16; off <<= 1)
                l[rt][r] += __shfl_xor(l[rt][r], off, 64);
        }

#pragma unroll
    for (int rt = 0; rt < 2; ++rt) {
#pragma unroll
        for (int r = 0; r < 4; ++r) {
            float linv = 1.f / l[rt][r];
            const size_t row = (size_t)n * HWD + q0 + rt * 16 + quad * 4 + r;
#pragma unroll
            for (int d = 0; d < 8; ++d) {
                float v = o[rt][d][r] * linv;
                v = fmaxf(v, 0.f);
                attn[row * MID + h * 128 + d * 16 + lrow] = (bf16_t)v;
            }
        }
    }
}

extern "C" void kernel_launch(void* const* d_in, const int* in_sizes, int n_in,
                              void* d_out, int out_size, void* d_ws, size_t ws_size,
                              hipStream_t stream) {
    const float* x       = (const float*)d_in[0];
    const float* conv1_w = (const float*)d_in[1];
    const float* gamma1  = (const float*)d_in[2];
    const float* beta1   = (const float*)d_in[3];
    const float* mean1   = (const float*)d_in[4];
    const float* var1    = (const float*)d_in[5];
    const float* qk_w    = (const float*)d_in[6];
    const float* v_w     = (const float*)d_in[7];
    const float* pos_h   = (const float*)d_in[8];
    const float* pos_w   = (const float*)d_in[9];
    const float* conv3_w = (const float*)d_in[10];
    const float* gamma3  = (const float*)d_in[11];
    const float* beta3   = (const float*)d_in[12];
    const float* mean3   = (const float*)d_in[13];
    const float* var3    = (const float*)d_in[14];
    float* out = (float*)d_out;

    char* ws = (char*)d_ws;
    size_t off = 0;
    auto carve = [&](size_t bytes) {
        void* p = ws + off;
        off += (bytes + 255) & ~(size_t)255;
        return p;
    };
    bf16_t* Xt    = (bf16_t*)carve((size_t)NB * HWD * CIN * 2);   // 64 MiB
    bf16_t* C1t   = (bf16_t*)carve((size_t)NB * HWD * MID * 2);   // 16 MiB
    bf16_t* QKt   = (bf16_t*)carve((size_t)NB * HWD * QKLD * 2);  // 32 MiB
    bf16_t* Vt    = (bf16_t*)carve((size_t)NB * 512 * HWD * 2);   // 16 MiB
    bf16_t* AttnT = (bf16_t*)carve((size_t)NB * HWD * MID * 2);   // 16 MiB
    bf16_t* W1b   = (bf16_t*)carve((size_t)512 * 2048 * 2);
    bf16_t* Wqkb  = (bf16_t*)carve((size_t)1024 * 512 * 2);
    bf16_t* Wvb   = (bf16_t*)carve((size_t)512 * 512 * 2);
    bf16_t* W3b   = (bf16_t*)carve((size_t)2048 * 512 * 2);
    float*  Emb   = (float*)carve((size_t)1024 * 128 * 4);

    prep_kernel<<<2048, 256, 0, stream>>>(conv1_w, qk_w, v_w, pos_h, pos_w, conv3_w,
                                          W1b, Wqkb, Wvb, W3b, Emb);

    transpose_x_kernel<<<dim3(64, 16, NB), 256, 0, stream>>>(x, Xt);

    // conv1 + BN + ReLU:  C1t[hw][512]
    gemm_bt<1><<<dim3(4, 8, NB), 256, 0, stream>>>(
        Xt, (long long)HWD * CIN, W1b, 0, CIN, MID,
        gamma1, beta1, mean1, var1, nullptr, 0, C1t, (long long)HWD * MID);

    // qk projection (+emb on k) AND v projection (transposed), one dispatch
    gemm_qkv<<<dim3(8, 12, NB), 256, 0, stream>>>(C1t, Wqkb, Wvb, Emb, QKt, Vt);

    attn_kernel<<<dim3(8, 4, NB), 256, 0, stream>>>(QKt, Vt, AttnT);

    // conv3 + BN + residual + ReLU -> out[co][hw] fp32
    gemm_bt<3><<<dim3(8, 16, NB), 256, 0, stream>>>(
        W3b, 0, AttnT, (long long)HWD * MID, MID, HWD,
        gamma3, beta3, mean3, var3, x, (long long)CIN * HWD, out, (long long)CIN * HWD);
}